// Round 9
// baseline (182.014 us; speedup 1.0000x reference)
//
#include <hip/hip_runtime.h>

typedef __bf16 bf16x8 __attribute__((ext_vector_type(8)));
typedef float f32x4 __attribute__((ext_vector_type(4)));
typedef unsigned short u16;
typedef unsigned int u32;
typedef u16 u16x4 __attribute__((ext_vector_type(4)));
typedef u16 u16x8 __attribute__((ext_vector_type(8)));

#define L2ALPHA (-0.014499569f)   // log2(0.99)

static __device__ __forceinline__ u16 f2bf(float f) {
    u32 u = __builtin_bit_cast(u32, f);
    return (u16)((u + 0x7FFFu + ((u >> 16) & 1u)) >> 16);
}

// async global->LDS, 16B per lane, dest must be wave-uniform-base + lane*16
static __device__ __forceinline__ void gl2lds16(const void* g, void* l) {
    __builtin_amdgcn_global_load_lds(
        (const __attribute__((address_space(1))) u32*)g,
        (__attribute__((address_space(3))) u32*)l, 16, 0, 0);
}

// ---------------------------------------------------------------------------
// Projection v5: zero-A-LDS. W panel staged once (one barrier); x read
// DIRECTLY in MFMA A-fragment layout (32B/lane, in-register cvt) -> no
// barriers, no As round-trip in the k-loop. grid 384 = 6 nb x 64 chunks,
// 4 m-tiles/block, all blocks co-resident (2/CU); nb-siblings share XCD.
// ---------------------------------------------------------------------------
__global__ __launch_bounds__(256, 2) void proj_kernel(
        const float* __restrict__ x, const float* __restrict__ Wq,
        const float* __restrict__ bias,
        u16* __restrict__ qb, u16* __restrict__ kb, u16* __restrict__ vb)
{
    __shared__ __align__(16) u16 Bs[32 * 128 * 8];   // 64 KB: [k8][col][e]

    const int tid = threadIdx.x, lane = tid & 63, w = tid >> 6;
    const int l = blockIdx.x;                 // 0..383
    const int nb = l >> 6;                    // 0..5  (l and l+64 share XCD)
    const int chunk = l & 63;                 // 0..63
    const int n0 = nb * 128;
    const int m = lane & 15, quad = lane >> 4;

    // ---- stage W panel (256 x 128 fp32 -> bf16 fragment order), once ----
    {
        const int col = tid & 127;
        const int khalf = tid >> 7;
        #pragma unroll
        for (int s = 0; s < 32; ++s) {
            int k0 = (khalf + 2 * s) * 4;
            u16x4 h;
            #pragma unroll
            for (int i = 0; i < 4; ++i)
                h[i] = f2bf(Wq[(k0 + i) * 768 + n0 + col]);
            *(u16x4*)&Bs[((k0 >> 3) * 128 + col) * 8 + (k0 & 7)] = h;
        }
    }
    __syncthreads();   // the only barrier

    const int b_d0 = (nb & 1) * 128;

    for (int it = 0; it < 4; ++it) {
        const int m0 = (chunk * 4 + it) * 128;
        // wave w owns rows m0+w*32 .. +31 (two 16-row groups), cols 0..127
        const float* xw = x + (size_t)(m0 + w * 32 + m) * 256 + quad * 8;

        f32x4 acc[2][8];
        #pragma unroll
        for (int rt = 0; rt < 2; ++rt)
            #pragma unroll
            for (int ct = 0; ct < 8; ++ct)
                acc[rt][ct] = f32x4{0.f, 0.f, 0.f, 0.f};

        #pragma unroll
        for (int kt = 0; kt < 8; ++kt) {
            bf16x8 af[2];
            #pragma unroll
            for (int rt = 0; rt < 2; ++rt) {
                const float* xp = xw + (size_t)rt * 16 * 256 + kt * 32;
                float4 a0 = *(const float4*)(xp);
                float4 a1 = *(const float4*)(xp + 4);
                u16x8 h;
                h[0]=f2bf(a0.x); h[1]=f2bf(a0.y); h[2]=f2bf(a0.z); h[3]=f2bf(a0.w);
                h[4]=f2bf(a1.x); h[5]=f2bf(a1.y); h[6]=f2bf(a1.z); h[7]=f2bf(a1.w);
                af[rt] = __builtin_bit_cast(bf16x8, h);
            }
            bf16x8 bfr[8];
            #pragma unroll
            for (int ct = 0; ct < 8; ++ct)
                bfr[ct] = *(const bf16x8*)&Bs[((kt * 4 + quad) * 128 + ct * 16 + m) * 8];
            #pragma unroll
            for (int rt = 0; rt < 2; ++rt)
                #pragma unroll
                for (int ct = 0; ct < 8; ++ct)
                    acc[rt][ct] = __builtin_amdgcn_mfma_f32_16x16x32_bf16(
                        af[rt], bfr[ct], acc[rt][ct], 0, 0, 0);
        }

        const int b = m0 >> 12;
        const int jbase = (m0 & 4095) + w * 32;

        if (nb < 2) {
            // Q: [row][d] bf16, pre-scaled by 1/sqrt(256)
            #pragma unroll
            for (int rt = 0; rt < 2; ++rt)
                #pragma unroll
                for (int ct = 0; ct < 8; ++ct) {
                    int coll = ct * 16 + m;
                    float bv = bias[b_d0 + coll];
                    #pragma unroll
                    for (int rr = 0; rr < 4; ++rr) {
                        int row = m0 + w * 32 + rt * 16 + quad * 4 + rr;
                        qb[(size_t)row * 256 + b_d0 + coll] = f2bf((acc[rt][ct][rr] + bv) * 0.0625f);
                    }
                }
        } else if (nb < 4) {
            // K fragment-order w/ even-odd split: [b][jt][j&1][k8][qk*16+(j>>1)][e]
            #pragma unroll
            for (int rt = 0; rt < 2; ++rt)
                #pragma unroll
                for (int ct = 0; ct < 8; ++ct) {
                    int d = b_d0 + ct * 16 + m;
                    float bv = bias[256 + d];
                    int k8 = d >> 5, qk = (d >> 3) & 3, e = d & 7;
                    #pragma unroll
                    for (int rr = 0; rr < 4; ++rr) {
                        int j = jbase + rt * 16 + quad * 4 + rr;
                        int jt = j >> 5, jj = j & 31;
                        kb[((((size_t)(b * 128 + jt) * 2 + (jj & 1)) * 8 + k8) * 64 + qk * 16 + (jj >> 1)) * 8 + e]
                            = f2bf(acc[rt][ct][rr] + bv);
                    }
                }
        } else {
            // V fragment-order: [b][jt][dt][qv*16+mv][e], e=j&7 -> u16x4 over rr
            #pragma unroll
            for (int rt = 0; rt < 2; ++rt)
                #pragma unroll
                for (int ct = 0; ct < 8; ++ct) {
                    int d = b_d0 + ct * 16 + m;
                    float bv = bias[512 + d];
                    int dt = d >> 4, mv = d & 15;
                    int j = jbase + rt * 16 + quad * 4;
                    int jt = j >> 5, qv = (j >> 3) & 3, e0 = j & 7;
                    u16x4 hv;
                    #pragma unroll
                    for (int rr = 0; rr < 4; ++rr) hv[rr] = f2bf(acc[rt][ct][rr] + bv);
                    *(u16x4*)&vb[(((size_t)(b * 128 + jt) * 16 + dt) * 64 + qv * 16 + mv) * 8 + e0] = hv;
                }
        }
    }
}

// ---------------------------------------------------------------------------
// Windowed flash-retention v5.1: t-parity wave specialization (as R8) with
// conflict-free combine epilogue ([wp][frag][lane][4] -> 16B/lane b128).
// grid 256 = 32 mt x 8 batches (batch = id%8 -> XCD-affine), block 512.
// ---------------------------------------------------------------------------
__global__ __launch_bounds__(512, 2) void attn_kernel(
        const u16* __restrict__ qb, const u16* __restrict__ kb,
        const u16* __restrict__ vb, float* __restrict__ out)
{
    __shared__ __align__(16) u16 KV[2][2][16384];  // [buf][tile-parity][K|V] 128 KB
    __shared__ __align__(16) u16 Ps[8 * 32 * 40];  // per-wave P (32 rows), 20 KB

    const int tid = threadIdx.x, lane = tid & 63, w = tid >> 6;   // w 0..7
    const int wp = w & 3, par = w >> 2;           // row-group, tile-parity
    const int l = blockIdx.x;
    const int b = l & 7;
    const int m0 = (l >> 3) * 128;                // l>>3 in [0,32)
    const int qrow0 = m0 + wp * 32;
    const int m = lane & 15, quad = lane >> 4;
    const size_t rowbase = (size_t)b * 4096;
    const size_t pbase = (size_t)b * 128;

    bf16x8 qf[2][8];
    #pragma unroll
    for (int rg = 0; rg < 2; ++rg)
        #pragma unroll
        for (int k8 = 0; k8 < 8; ++k8)
            qf[rg][k8] = *(const bf16x8*)(qb + (rowbase + qrow0 + rg * 16 + m) * 256 + k8 * 32 + quad * 8);

    f32x4 acc[2][16];
    #pragma unroll
    for (int rg = 0; rg < 2; ++rg)
        #pragma unroll
        for (int dt = 0; dt < 16; ++dt)
            acc[rg][dt] = f32x4{0.f, 0.f, 0.f, 0.f};

    int t0 = (m0 - 1024) >> 5; if (t0 < 0) t0 = 0;
    const int t1 = (m0 >> 5) + 3;
    const int nIter = (t1 - t0 + 2) >> 1;

    // initial stage: tiles (t0, t0+1) into buffer 0
    {
        const u16* kpA = kb + (pbase + t0) * 8192;
        const u16* vpA = vb + (pbase + t0) * 8192;
        #pragma unroll
        for (int s = 0; s < 2; ++s) {
            int c = tid + 512 * s;                // 0..1023
            gl2lds16(kpA + (size_t)c * 8, &KV[0][0][c * 8]);
            gl2lds16(vpA + (size_t)c * 8, &KV[0][0][8192 + c * 8]);
            gl2lds16(kpA + 8192 + (size_t)c * 8, &KV[0][1][c * 8]);
            gl2lds16(vpA + 8192 + (size_t)c * 8, &KV[0][1][8192 + c * 8]);
        }
    }

    int p = 0;
    for (int it = 0; it < nIter; ++it) {
        __syncthreads();   // drains DMA into buf p; all waves done with buf p^1
        if (it + 1 < nIter) {
            const int ta = t0 + 2 * (it + 1);
            const bool haveB = (ta + 1 <= t1);    // block-uniform
            const u16* kpA = kb + (pbase + ta) * 8192;
            const u16* vpA = vb + (pbase + ta) * 8192;
            #pragma unroll
            for (int s = 0; s < 2; ++s) {
                int c = tid + 512 * s;
                gl2lds16(kpA + (size_t)c * 8, &KV[p ^ 1][0][c * 8]);
                gl2lds16(vpA + (size_t)c * 8, &KV[p ^ 1][0][8192 + c * 8]);
                if (haveB) {
                    gl2lds16(kpA + 8192 + (size_t)c * 8, &KV[p ^ 1][1][c * 8]);
                    gl2lds16(vpA + 8192 + (size_t)c * 8, &KV[p ^ 1][1][8192 + c * 8]);
                }
            }
        }

        const int t = t0 + 2 * it + par;
        const int j0 = t * 32;
        if (t <= t1 && j0 <= qrow0 + 31 && j0 + 1055 >= qrow0) {
            const u16* Kt = &KV[p][par][0];
            const u16* Vt = &KV[p][par][8192];

            f32x4 sA0{0.f,0.f,0.f,0.f}, sA1{0.f,0.f,0.f,0.f};
            f32x4 sB0{0.f,0.f,0.f,0.f}, sB1{0.f,0.f,0.f,0.f};
            #pragma unroll
            for (int k8 = 0; k8 < 8; ++k8) {
                bf16x8 bf0 = *(const bf16x8*)&Kt[(k8 * 64 + lane) * 8];
                sA0 = __builtin_amdgcn_mfma_f32_16x16x32_bf16(qf[0][k8], bf0, sA0, 0, 0, 0);
                sA1 = __builtin_amdgcn_mfma_f32_16x16x32_bf16(qf[1][k8], bf0, sA1, 0, 0, 0);
            }
            #pragma unroll
            for (int k8 = 0; k8 < 8; ++k8) {
                bf16x8 bf1 = *(const bf16x8*)&Kt[((8 + k8) * 64 + lane) * 8];
                sB0 = __builtin_amdgcn_mfma_f32_16x16x32_bf16(qf[0][k8], bf1, sB0, 0, 0, 0);
                sB1 = __builtin_amdgcn_mfma_f32_16x16x32_bf16(qf[1][k8], bf1, sB1, 0, 0, 0);
            }

            // decay-mask; sA = even keys (j0+2m), sB = odd keys (j0+2m+1)
            #pragma unroll
            for (int rg = 0; rg < 2; ++rg) {
                f32x4 sh0 = rg ? sA1 : sA0;
                f32x4 sh1 = rg ? sB1 : sB0;
                #pragma unroll
                for (int rr = 0; rr < 4; ++rr) {
                    int i = qrow0 + rg * 16 + quad * 4 + rr;
                    int dd0 = i - (j0 + 2 * m);
                    int dd1 = dd0 - 1;
                    float w0 = (dd0 >= 0) ? __builtin_amdgcn_exp2f((float)dd0 * L2ALPHA) : 0.0f;
                    float w1 = (dd1 >= 0) ? __builtin_amdgcn_exp2f((float)dd1 * L2ALPHA) : 0.0f;
                    int rowb = (w * 32 + rg * 16 + quad * 4 + rr) * 40;
                    u32 pv = (u32)f2bf(sh0[rr] * w0) | ((u32)f2bf(sh1[rr] * w1) << 16);
                    *(u32*)&Ps[rowb + 2 * m] = pv;
                }
            }
            asm volatile("s_waitcnt lgkmcnt(0)" ::: "memory");  // wave-local P ready

            bf16x8 pa0 = *(const bf16x8*)&Ps[(w * 32 + m) * 40 + quad * 8];
            bf16x8 pa1 = *(const bf16x8*)&Ps[(w * 32 + 16 + m) * 40 + quad * 8];

            #pragma unroll
            for (int dt = 0; dt < 16; ++dt) {
                bf16x8 vf = *(const bf16x8*)&Vt[(dt * 64 + lane) * 8];
                acc[0][dt] = __builtin_amdgcn_mfma_f32_16x16x32_bf16(pa0, vf, acc[0][dt], 0, 0, 0);
                acc[1][dt] = __builtin_amdgcn_mfma_f32_16x16x32_bf16(pa1, vf, acc[1][dt], 0, 0, 0);
            }
        }
        p ^= 1;
    }

    // in-block combine via retired staging LDS: [wp][frag 0..31][lane][4]
    // 16B/lane canonical b128 -> conflict-free
    __syncthreads();
    float* Comb = (float*)&KV[0][0][0];           // 32768 floats exactly
    if (par == 1) {
        float* dst = Comb + ((size_t)wp * 32 * 64 + lane) * 4;
        #pragma unroll
        for (int rg = 0; rg < 2; ++rg)
            #pragma unroll
            for (int dt = 0; dt < 16; ++dt)
                *(f32x4*)(dst + (rg * 16 + dt) * 256) = acc[rg][dt];
    }
    __syncthreads();
    if (par == 0) {
        const float* src = Comb + ((size_t)wp * 32 * 64 + lane) * 4;
        #pragma unroll
        for (int rg = 0; rg < 2; ++rg)
            #pragma unroll
            for (int dt = 0; dt < 16; ++dt) {
                f32x4 o = acc[rg][dt] + *(const f32x4*)(src + (rg * 16 + dt) * 256);
                #pragma unroll
                for (int rr = 0; rr < 4; ++rr)
                    out[(rowbase + qrow0 + rg * 16 + quad * 4 + rr) * 256 + dt * 16 + m] = o[rr];
            }
    }
}

// ---------------------------------------------------------------------------
extern "C" void kernel_launch(void* const* d_in, const int* in_sizes, int n_in,
                              void* d_out, int out_size, void* d_ws, size_t ws_size,
                              hipStream_t stream) {
    (void)in_sizes; (void)n_in; (void)out_size; (void)ws_size;
    const float* x    = (const float*)d_in[0];
    const float* Wq   = (const float*)d_in[1];
    const float* bias = (const float*)d_in[2];
    float* outp = (float*)d_out;

    const size_t per = (size_t)8 * 4096 * 256;   // elems per q/k/v buffer (48 MB total)
    u16* qb = (u16*)d_ws;
    u16* kb = qb + per;
    u16* vb = kb + per;

    proj_kernel<<<384, 256, 0, stream>>>(x, Wq, bias, qb, kb, vb);
    attn_kernel<<<256, 512, 0, stream>>>(qb, kb, vb, outp);
}